// Round 3
// baseline (472.165 us; speedup 1.0000x reference)
//
#include <hip/hip_runtime.h>

#define NB 128      // batch
#define NS 100      // samples
#define NPRED 24
#define NHID 256
#define NSTEPS 16
#define NCTX 96
// rows M = NS*NB = 12800; 16 rows per wave, 4 waves/block -> 200 blocks

typedef float f32x4 __attribute__((ext_vector_type(4)));
typedef short bf16x8 __attribute__((ext_vector_type(8)));

__device__ __forceinline__ unsigned short f2bf(float f) {
    union { float f; unsigned u; } v; v.f = f;
    return (unsigned short)((v.u + 0x7fffu + ((v.u >> 16) & 1u)) >> 16);
}
__device__ __forceinline__ unsigned pk2(float lo, float hi) {
    return (unsigned)f2bf(lo) | ((unsigned)f2bf(hi) << 16);
}
__device__ __forceinline__ bf16x8 mk8(unsigned a, unsigned b, unsigned c, unsigned d) {
    union { unsigned u[4]; bf16x8 v; } x;
    x.u[0] = a; x.u[1] = b; x.u[2] = c; x.u[3] = d;
    return x.v;
}

// k-slot permutation within a 32-wide k-block at (lane l, elem e):
//   k_local = 16*(e>>2) + 4*(l>>4) + (e&3)
// Applied identically to A (weights) and B (activations) fragments -> correct
// for any lane-symmetric hardware k-map (bijection argument). Verified R2.

__global__ __launch_bounds__(256, 1) void fm_kernel(
    const float* __restrict__ past_target,
    const float* __restrict__ z0g,
    const float* __restrict__ W1, const float* __restrict__ b1,
    const float* __restrict__ W2, const float* __restrict__ b2,
    const float* __restrict__ W3, const float* __restrict__ b3,
    float* __restrict__ out) {
    // LDS layout (ushorts): W1F [0,8192) | W2F [8192,73728) | W3F [73728,81920)
    // = 163840 B = 160 KiB (full CU LDS; 1 block/CU by construction)
    __shared__ __attribute__((aligned(16))) unsigned short lds[81920];

    const int tid = threadIdx.x;

    // ---- stage permuted bf16 frag images into LDS (one-time) ----
    for (int idx = tid; idx < 8192; idx += 256) {        // W1F (z rows 0..23, t row 24)
        int T = idx >> 9, ll = (idx >> 3) & 63, e = idx & 7;
        int k = 16 * (e >> 2) + 4 * (ll >> 4) + (e & 3);
        int m = 16 * T + (ll & 15);
        lds[idx] = (k <= 24) ? f2bf(W1[k * NHID + m]) : (unsigned short)0;
    }
    for (int idx = tid; idx < 65536; idx += 256) {       // W2F
        int ks = idx >> 13, T = (idx >> 9) & 15, ll = (idx >> 3) & 63, e = idx & 7;
        int k = 32 * ks + 16 * (e >> 2) + 4 * (ll >> 4) + (e & 3);
        int m = 16 * T + (ll & 15);
        lds[8192 + idx] = f2bf(W2[k * NHID + m]);
    }
    for (int idx = tid; idx < 8192; idx += 256) {        // W3F (cols >=24 zero-pad)
        int ks = idx >> 10, T = (idx >> 9) & 1, ll = (idx >> 3) & 63, e = idx & 7;
        int k = 32 * ks + 16 * (e >> 2) + 4 * (ll >> 4) + (e & 3);
        int m = 16 * T + (ll & 15);
        lds[73728 + idx] = (m < NPRED) ? f2bf(W3[k * NPRED + m]) : (unsigned short)0;
    }

    const int wave = tid >> 6;
    const int l = tid & 63;
    const int q = l >> 4, p = l & 15;
    const int g = blockIdx.x * 4 + wave;   // 0..799
    const int R = g * 16 + p;              // global row 0..12799
    const int s = R >> 7, b = R & 127;

    // ---- per-lane loc (scale) ----
    const float* ctx = past_target + b * NCTX;
    float asum = 0.f;
    for (int k = 0; k < NCTX; k++) asum += fabsf(ctx[k]);
    float loc = fmaxf(asum / (float)NCTX, 1e-6f);
    float inv = 1.f / loc;

    // ---- fp32 context bias: cb[T] = b1[...] + sum_k sctx[k]*W1[26+k][...] ----
    f32x4 cb[16];
#pragma unroll
    for (int T = 0; T < 16; T++) cb[T] = *(const f32x4*)(b1 + 16 * T + 4 * q);
    for (int k = 0; k < NCTX; k++) {
        float sx = ctx[k] * inv;
        const f32x4* wr = (const f32x4*)(W1 + (26 + k) * NHID + 4 * q);
#pragma unroll
        for (int T = 0; T < 16; T++) {
            f32x4 w = wr[4 * T];
            cb[T].x += sx * w.x; cb[T].y += sx * w.y;
            cb[T].z += sx * w.z; cb[T].w += sx * w.w;
        }
    }

    // ---- z state in C'-layout: zs0 = ch 4q..4q+3, zs1 = ch 16+4q.. (q<2), else 0 ----
    f32x4 zs0, zs1;
    {
        const f32x4* zr = (const f32x4*)(z0g + R * NPRED);
        zs0 = zr[q];
        f32x4 zz = {0.f, 0.f, 0.f, 0.f};
        zs1 = zz;
        if (q < 2) zs1 = zr[4 + q];
    }

    // ---- bias A-frag pieces (k-slot 0 lives at lanes l<16, elem 0) ----
    unsigned b2v[16];
#pragma unroll
    for (int T = 0; T < 16; T++)
        b2v[T] = (l < 16) ? (unsigned)f2bf(b2[16 * T + p]) : 0u;
    unsigned b3v0 = (l < 16) ? (unsigned)f2bf(b3[p]) : 0u;
    unsigned b3v1 = (l < 16 && p < 8) ? (unsigned)f2bf(b3[16 + p]) : 0u;
    const unsigned bone = (l < 16) ? 0x3f80u : 0u;  // bf16 1.0 at slot (e=0)

    __syncthreads();

    const unsigned short* W1F = lds;
    const unsigned short* W2F = lds + 8192;
    const unsigned short* W3F = lds + 73728;
    const int l8 = l * 8;

    const float dt = 1.f / (float)NSTEPS;
#pragma unroll 1
    for (int step = 0; step < NSTEPS; step++) {
        float t = 1.f - (float)step * dt;
        // B-frag from z; channel 24 (q==2, e==4) carries t
        float z10 = (q == 2) ? t : zs1.x;
        bf16x8 bz = mk8(pk2(zs0.x, zs0.y), pk2(zs0.z, zs0.w),
                        pk2(z10, zs1.y), pk2(zs1.z, zs1.w));

        // ---- layer 1: h1 = relu(z@W1z + t*w1t + cbias) -> bh (B-frag words) ----
        unsigned bh[32];
#pragma unroll
        for (int T = 0; T < 16; T++) {
            bf16x8 a = *(const bf16x8*)(W1F + T * 512 + l8);
            f32x4 h = __builtin_amdgcn_mfma_f32_16x16x32_bf16(a, bz, cb[T], 0, 0, 0);
            h.x = fmaxf(h.x, 0.f); h.y = fmaxf(h.y, 0.f);
            h.z = fmaxf(h.z, 0.f); h.w = fmaxf(h.w, 0.f);
            bh[2 * T]     = pk2(h.x, h.y);
            bh[2 * T + 1] = pk2(h.z, h.w);
        }

        // ---- layers 2+3 fused: T in groups of 4; h2 pairs feed v imm. ----
        f32x4 v0 = {0.f, 0.f, 0.f, 0.f}, v1 = {0.f, 0.f, 0.f, 0.f};
#pragma unroll
        for (int j = 0; j < 4; j++) {
            f32x4 a0 = {0.f, 0.f, 0.f, 0.f}, a1 = a0, a2 = a0, a3 = a0;
#pragma unroll
            for (int ks = 0; ks < 8; ks++) {
                bf16x8 bb = mk8(bh[4 * ks], bh[4 * ks + 1], bh[4 * ks + 2], bh[4 * ks + 3]);
                const unsigned short* base = W2F + (ks * 16 + 4 * j) * 512 + l8;
                a0 = __builtin_amdgcn_mfma_f32_16x16x32_bf16(*(const bf16x8*)(base), bb, a0, 0, 0, 0);
                a1 = __builtin_amdgcn_mfma_f32_16x16x32_bf16(*(const bf16x8*)(base + 512), bb, a1, 0, 0, 0);
                a2 = __builtin_amdgcn_mfma_f32_16x16x32_bf16(*(const bf16x8*)(base + 1024), bb, a2, 0, 0, 0);
                a3 = __builtin_amdgcn_mfma_f32_16x16x32_bf16(*(const bf16x8*)(base + 1536), bb, a3, 0, 0, 0);
            }
            bf16x8 bfo = mk8(bone, 0u, 0u, 0u);
            a0 = __builtin_amdgcn_mfma_f32_16x16x32_bf16(mk8(b2v[4 * j], 0u, 0u, 0u), bfo, a0, 0, 0, 0);
            a1 = __builtin_amdgcn_mfma_f32_16x16x32_bf16(mk8(b2v[4 * j + 1], 0u, 0u, 0u), bfo, a1, 0, 0, 0);
            a2 = __builtin_amdgcn_mfma_f32_16x16x32_bf16(mk8(b2v[4 * j + 2], 0u, 0u, 0u), bfo, a2, 0, 0, 0);
            a3 = __builtin_amdgcn_mfma_f32_16x16x32_bf16(mk8(b2v[4 * j + 3], 0u, 0u, 0u), bfo, a3, 0, 0, 0);
            a0.x = fmaxf(a0.x, 0.f); a0.y = fmaxf(a0.y, 0.f); a0.z = fmaxf(a0.z, 0.f); a0.w = fmaxf(a0.w, 0.f);
            a1.x = fmaxf(a1.x, 0.f); a1.y = fmaxf(a1.y, 0.f); a1.z = fmaxf(a1.z, 0.f); a1.w = fmaxf(a1.w, 0.f);
            a2.x = fmaxf(a2.x, 0.f); a2.y = fmaxf(a2.y, 0.f); a2.z = fmaxf(a2.z, 0.f); a2.w = fmaxf(a2.w, 0.f);
            a3.x = fmaxf(a3.x, 0.f); a3.y = fmaxf(a3.y, 0.f); a3.z = fmaxf(a3.z, 0.f); a3.w = fmaxf(a3.w, 0.f);
            // layer3: ks slots 2j (from a0,a1) and 2j+1 (from a2,a3)
            bf16x8 bb3a = mk8(pk2(a0.x, a0.y), pk2(a0.z, a0.w), pk2(a1.x, a1.y), pk2(a1.z, a1.w));
            bf16x8 bb3b = mk8(pk2(a2.x, a2.y), pk2(a2.z, a2.w), pk2(a3.x, a3.y), pk2(a3.z, a3.w));
            const unsigned short* b3base = W3F + (2 * j) * 1024 + l8;
            v0 = __builtin_amdgcn_mfma_f32_16x16x32_bf16(*(const bf16x8*)(b3base), bb3a, v0, 0, 0, 0);
            v1 = __builtin_amdgcn_mfma_f32_16x16x32_bf16(*(const bf16x8*)(b3base + 512), bb3a, v1, 0, 0, 0);
            v0 = __builtin_amdgcn_mfma_f32_16x16x32_bf16(*(const bf16x8*)(b3base + 1024), bb3b, v0, 0, 0, 0);
            v1 = __builtin_amdgcn_mfma_f32_16x16x32_bf16(*(const bf16x8*)(b3base + 1536), bb3b, v1, 0, 0, 0);
        }
        {
            bf16x8 bfo = mk8(bone, 0u, 0u, 0u);
            v0 = __builtin_amdgcn_mfma_f32_16x16x32_bf16(mk8(b3v0, 0u, 0u, 0u), bfo, v0, 0, 0, 0);
            v1 = __builtin_amdgcn_mfma_f32_16x16x32_bf16(mk8(b3v1, 0u, 0u, 0u), bfo, v1, 0, 0, 0);
        }

        // ---- Euler update (pad channels have v==0, stay 0) ----
        zs0.x -= dt * v0.x; zs0.y -= dt * v0.y; zs0.z -= dt * v0.z; zs0.w -= dt * v0.w;
        zs1.x -= dt * v1.x; zs1.y -= dt * v1.y; zs1.z -= dt * v1.z; zs1.w -= dt * v1.w;
    }

    // ---- store: out[b][s][c] = z[c] * loc ----
    float* op = out + b * (NS * NPRED) + s * NPRED;
    f32x4 o0 = zs0 * loc;
    *(f32x4*)(op + 4 * q) = o0;
    if (q < 2) {
        f32x4 o1 = zs1 * loc;
        *(f32x4*)(op + 16 + 4 * q) = o1;
    }
}

extern "C" void kernel_launch(void* const* d_in, const int* in_sizes, int n_in,
                              void* d_out, int out_size, void* d_ws, size_t ws_size,
                              hipStream_t stream) {
    const float* past_target = (const float*)d_in[0];
    // d_in[1] past_observed_values: not used by the reference math
    const float* z0 = (const float*)d_in[2];
    const float* W1 = (const float*)d_in[3];
    const float* b1 = (const float*)d_in[4];
    const float* W2 = (const float*)d_in[5];
    const float* b2 = (const float*)d_in[6];
    const float* W3 = (const float*)d_in[7];
    const float* b3 = (const float*)d_in[8];

    fm_kernel<<<200, 256, 0, stream>>>(past_target, z0, W1, b1, W2, b2, W3, b3,
                                       (float*)d_out);
}

// Round 4
// 284.283 us; speedup vs baseline: 1.6609x; 1.6609x over previous
//
#include <hip/hip_runtime.h>

#define NB 128
#define NS 100
#define NPRED 24
#define NHID 256
#define NSTEPS 16
#define NCTX 96
// rows M = NS*NB = 12800; 16 rows/wave, 4 waves/block -> 200 blocks

typedef float f32x4 __attribute__((ext_vector_type(4)));
typedef short bf16x8 __attribute__((ext_vector_type(8)));

__device__ __forceinline__ unsigned short f2bf(float f) {
    union { float f; unsigned u; } v; v.f = f;
    return (unsigned short)((v.u + 0x7fffu + ((v.u >> 16) & 1u)) >> 16);
}
__device__ __forceinline__ unsigned pk2(float lo, float hi) {
    return (unsigned)f2bf(lo) | ((unsigned)f2bf(hi) << 16);
}
__device__ __forceinline__ bf16x8 mk8(unsigned a, unsigned b, unsigned c, unsigned d) {
    union { unsigned u[4]; bf16x8 v; } x;
    x.u[0] = a; x.u[1] = b; x.u[2] = c; x.u[3] = d;
    return x.v;
}
__device__ __forceinline__ f32x4 bf4_to_f32x4(const unsigned short* pA) {
    uint2 uu = *(const uint2*)pA;
    union { unsigned u; float f; } c0, c1, c2, c3;
    c0.u = uu.x << 16; c1.u = uu.x & 0xffff0000u;
    c2.u = uu.y << 16; c3.u = uu.y & 0xffff0000u;
    f32x4 r; r.x = c0.f; r.y = c1.f; r.z = c2.f; r.w = c3.f;
    return r;
}

// k-slot permutation within a 32-wide k-block at (lane l, elem e):
//   k_local = 16*(e>>2) + 4*(l>>4) + (e&3)
// Applied identically to A and B fragments -> correct for any lane-symmetric
// hardware k-map. Numerically verified in R2/R3.

// prep: W1F [0,8192) + W3F [8192,16384) permuted bf16 frag images -> d_ws (32 KB)
__global__ void prep_kernel(const float* __restrict__ W1,
                            const float* __restrict__ W3,
                            unsigned short* __restrict__ wsf) {
    int i = blockIdx.x * 256 + threadIdx.x;   // 0..16383
    if (i < 8192) {
        int T = i >> 9, ll = (i >> 3) & 63, e = i & 7;
        int k = 16 * (e >> 2) + 4 * (ll >> 4) + (e & 3);
        int m = 16 * T + (ll & 15);
        wsf[i] = (k <= 24) ? f2bf(W1[k * NHID + m]) : (unsigned short)0;
    } else {
        int idx = i - 8192;
        int ks = idx >> 10, T = (idx >> 9) & 1, ll = (idx >> 3) & 63, e = idx & 7;
        int k = 32 * ks + 16 * (e >> 2) + 4 * (ll >> 4) + (e & 3);
        int m = 16 * T + (ll & 15);
        wsf[i] = (m < NPRED) ? f2bf(W3[k * NPRED + m]) : (unsigned short)0;
    }
}

__global__ __launch_bounds__(256, 1) void fm_kernel(
    const float* __restrict__ past_target,
    const float* __restrict__ z0g,
    const float* __restrict__ W1, const float* __restrict__ b1,
    const float* __restrict__ W2, const float* __restrict__ b2,
    const float* __restrict__ b3,
    const unsigned short* __restrict__ wsf,
    float* __restrict__ out) {
    // LDS (ushorts): cbF [0,16384) | W2F [16384,81920)  = 163840 B = 160 KiB
    __shared__ __attribute__((aligned(16))) unsigned short lds[81920];

    const int tid = threadIdx.x;
    const int s_idx = blockIdx.x >> 1;          // sample index (uniform per block)
    const int b_base = (blockIdx.x & 1) * 64;   // batch base (uniform per block)

    // ---- stage W2F into LDS ----
    for (int idx = tid; idx < 65536; idx += 256) {
        int ks = idx >> 13, T = (idx >> 9) & 15, ll = (idx >> 3) & 63, e = idx & 7;
        int k = 32 * ks + 16 * (e >> 2) + 4 * (ll >> 4) + (e & 3);
        int m = 16 * T + (ll & 15);
        lds[16384 + idx] = f2bf(W2[k * NHID + m]);
    }

    // ---- cooperative fp32 cbias -> bf16 C-fragments in cbF ----
    // 4 threads per row: thread handles one 64-wide j-quarter of one row.
    {
        const int bloc = tid >> 2;       // row-in-block 0..63
        const int quarter = tid & 3;     // hidden quarter
        const int bb = b_base + bloc;
        const float* ctxp = past_target + bb * NCTX;
        float asum = 0.f;
        for (int k = 0; k < NCTX; k++) asum += fabsf(ctxp[k]);
        float inv = 1.f / fmaxf(asum * (1.f / (float)NCTX), 1e-6f);
        f32x4 acc[16];
        const float* b1p = b1 + quarter * 64;
#pragma unroll
        for (int u = 0; u < 16; u++) acc[u] = *(const f32x4*)(b1p + 4 * u);
        for (int k = 0; k < NCTX; k++) {
            float sx = ctxp[k] * inv;
            const f32x4* wr = (const f32x4*)(W1 + (26 + k) * NHID + quarter * 64);
#pragma unroll
            for (int u = 0; u < 16; u++) {
                f32x4 w = wr[u];
                acc[u].x += sx * w.x; acc[u].y += sx * w.y;
                acc[u].z += sx * w.z; acc[u].w += sx * w.w;
            }
        }
        const int wv = bloc >> 4, pp = bloc & 15;
#pragma unroll
        for (int u = 0; u < 16; u++) {
            int T = quarter * 4 + (u >> 2), qq = u & 3;
            int base = wv * 4096 + T * 256 + qq * 64 + pp * 4;
            lds[base + 0] = f2bf(acc[u].x);
            lds[base + 1] = f2bf(acc[u].y);
            lds[base + 2] = f2bf(acc[u].z);
            lds[base + 3] = f2bf(acc[u].w);
        }
    }

    const int wave = tid >> 6;
    const int l = tid & 63;
    const int q = l >> 4, p = l & 15;
    const int b = b_base + wave * 16 + p;
    const int R = s_idx * NB + b;               // global row

    // ---- z state in C'-layout ----
    f32x4 zs0, zs1;
    {
        const f32x4* zr = (const f32x4*)(z0g + R * NPRED);
        zs0 = zr[q];
        f32x4 zz = {0.f, 0.f, 0.f, 0.f};
        zs1 = zz;
        if (q < 2) zs1 = zr[4 + q];
    }

    // ---- bias A-frag words (k-slot 0 at lanes l<16, elem 0) ----
    unsigned b2v[16];
#pragma unroll
    for (int T = 0; T < 16; T++)
        b2v[T] = (l < 16) ? (unsigned)f2bf(b2[16 * T + p]) : 0u;
    unsigned b3v0 = (l < 16) ? (unsigned)f2bf(b3[p]) : 0u;
    unsigned b3v1 = (l < 16 && p < 8) ? (unsigned)f2bf(b3[16 + p]) : 0u;
    const unsigned bone = (l < 16) ? 0x3f80u : 0u;

    __syncthreads();

    const int l8 = l * 8;
    const unsigned short* cb_base = lds + wave * 4096 + q * 64 + p * 4;
    const unsigned short* w2_base = lds + 16384 + l8;
    const unsigned short* w1g = wsf + l8;
    const unsigned short* w3g = wsf + 8192 + l8;

    const float dt = 1.f / (float)NSTEPS;
#pragma unroll 1
    for (int step = 0; step < NSTEPS; step++) {
        // launder invariant base pointers so LICM can't hoist frag loads
        const unsigned short* w1p = w1g;    asm volatile("" : "+v"(w1p));
        const unsigned short* w3p = w3g;    asm volatile("" : "+v"(w3p));
        const unsigned short* w2p = w2_base; asm volatile("" : "+v"(w2p));
        const unsigned short* cbp = cb_base; asm volatile("" : "+v"(cbp));

        float t = 1.f - (float)step * dt;
        float z10 = (q == 2) ? t : zs1.x;   // channel 24 carries t
        bf16x8 bz = mk8(pk2(zs0.x, zs0.y), pk2(zs0.z, zs0.w),
                        pk2(z10, zs1.y), pk2(zs1.z, zs1.w));

        // ---- layer 1: h1 = relu(z@W1z + t*w1t + cbias) ----
        unsigned bh[32];
#pragma unroll
        for (int T = 0; T < 16; T++) {
            bf16x8 a = *(const bf16x8*)(w1p + T * 512);
            f32x4 c = bf4_to_f32x4(cbp + T * 256);
            f32x4 h = __builtin_amdgcn_mfma_f32_16x16x32_bf16(a, bz, c, 0, 0, 0);
            h.x = fmaxf(h.x, 0.f); h.y = fmaxf(h.y, 0.f);
            h.z = fmaxf(h.z, 0.f); h.w = fmaxf(h.w, 0.f);
            bh[2 * T]     = pk2(h.x, h.y);
            bh[2 * T + 1] = pk2(h.z, h.w);
        }

        // ---- layers 2+3 fused ----
        f32x4 v0 = {0.f, 0.f, 0.f, 0.f}, v1 = {0.f, 0.f, 0.f, 0.f};
#pragma unroll
        for (int j = 0; j < 4; j++) {
            f32x4 a0 = {0.f, 0.f, 0.f, 0.f}, a1 = a0, a2 = a0, a3 = a0;
#pragma unroll
            for (int ks = 0; ks < 8; ks++) {
                bf16x8 bb = mk8(bh[4 * ks], bh[4 * ks + 1], bh[4 * ks + 2], bh[4 * ks + 3]);
                const unsigned short* base = w2p + (ks * 16 + 4 * j) * 512;
                a0 = __builtin_amdgcn_mfma_f32_16x16x32_bf16(*(const bf16x8*)(base), bb, a0, 0, 0, 0);
                a1 = __builtin_amdgcn_mfma_f32_16x16x32_bf16(*(const bf16x8*)(base + 512), bb, a1, 0, 0, 0);
                a2 = __builtin_amdgcn_mfma_f32_16x16x32_bf16(*(const bf16x8*)(base + 1024), bb, a2, 0, 0, 0);
                a3 = __builtin_amdgcn_mfma_f32_16x16x32_bf16(*(const bf16x8*)(base + 1536), bb, a3, 0, 0, 0);
            }
            bf16x8 bfo = mk8(bone, 0u, 0u, 0u);
            a0 = __builtin_amdgcn_mfma_f32_16x16x32_bf16(mk8(b2v[4 * j], 0u, 0u, 0u), bfo, a0, 0, 0, 0);
            a1 = __builtin_amdgcn_mfma_f32_16x16x32_bf16(mk8(b2v[4 * j + 1], 0u, 0u, 0u), bfo, a1, 0, 0, 0);
            a2 = __builtin_amdgcn_mfma_f32_16x16x32_bf16(mk8(b2v[4 * j + 2], 0u, 0u, 0u), bfo, a2, 0, 0, 0);
            a3 = __builtin_amdgcn_mfma_f32_16x16x32_bf16(mk8(b2v[4 * j + 3], 0u, 0u, 0u), bfo, a3, 0, 0, 0);
            a0.x = fmaxf(a0.x, 0.f); a0.y = fmaxf(a0.y, 0.f); a0.z = fmaxf(a0.z, 0.f); a0.w = fmaxf(a0.w, 0.f);
            a1.x = fmaxf(a1.x, 0.f); a1.y = fmaxf(a1.y, 0.f); a1.z = fmaxf(a1.z, 0.f); a1.w = fmaxf(a1.w, 0.f);
            a2.x = fmaxf(a2.x, 0.f); a2.y = fmaxf(a2.y, 0.f); a2.z = fmaxf(a2.z, 0.f); a2.w = fmaxf(a2.w, 0.f);
            a3.x = fmaxf(a3.x, 0.f); a3.y = fmaxf(a3.y, 0.f); a3.z = fmaxf(a3.z, 0.f); a3.w = fmaxf(a3.w, 0.f);
            bf16x8 bb3a = mk8(pk2(a0.x, a0.y), pk2(a0.z, a0.w), pk2(a1.x, a1.y), pk2(a1.z, a1.w));
            bf16x8 bb3b = mk8(pk2(a2.x, a2.y), pk2(a2.z, a2.w), pk2(a3.x, a3.y), pk2(a3.z, a3.w));
            const unsigned short* b3base = w3p + (2 * j) * 1024;
            v0 = __builtin_amdgcn_mfma_f32_16x16x32_bf16(*(const bf16x8*)(b3base), bb3a, v0, 0, 0, 0);
            v1 = __builtin_amdgcn_mfma_f32_16x16x32_bf16(*(const bf16x8*)(b3base + 512), bb3a, v1, 0, 0, 0);
            v0 = __builtin_amdgcn_mfma_f32_16x16x32_bf16(*(const bf16x8*)(b3base + 1024), bb3b, v0, 0, 0, 0);
            v1 = __builtin_amdgcn_mfma_f32_16x16x32_bf16(*(const bf16x8*)(b3base + 1536), bb3b, v1, 0, 0, 0);
        }
        {
            bf16x8 bfo = mk8(bone, 0u, 0u, 0u);
            v0 = __builtin_amdgcn_mfma_f32_16x16x32_bf16(mk8(b3v0, 0u, 0u, 0u), bfo, v0, 0, 0, 0);
            v1 = __builtin_amdgcn_mfma_f32_16x16x32_bf16(mk8(b3v1, 0u, 0u, 0u), bfo, v1, 0, 0, 0);
        }

        // ---- Euler update (pad channels keep v==0) ----
        zs0.x -= dt * v0.x; zs0.y -= dt * v0.y; zs0.z -= dt * v0.z; zs0.w -= dt * v0.w;
        zs1.x -= dt * v1.x; zs1.y -= dt * v1.y; zs1.z -= dt * v1.z; zs1.w -= dt * v1.w;
    }

    // ---- per-lane loc (computed post-loop to keep loop pressure low) ----
    const float* ctxl = past_target + b * NCTX;
    float asum = 0.f;
    for (int k = 0; k < NCTX; k++) asum += fabsf(ctxl[k]);
    float loc = fmaxf(asum * (1.f / (float)NCTX), 1e-6f);

    // ---- store: out[b][s][c] = z[c] * loc ----
    float* op = out + b * (NS * NPRED) + s_idx * NPRED;
    f32x4 o0 = zs0 * loc;
    *(f32x4*)(op + 4 * q) = o0;
    if (q < 2) {
        f32x4 o1 = zs1 * loc;
        *(f32x4*)(op + 16 + 4 * q) = o1;
    }
}

extern "C" void kernel_launch(void* const* d_in, const int* in_sizes, int n_in,
                              void* d_out, int out_size, void* d_ws, size_t ws_size,
                              hipStream_t stream) {
    const float* past_target = (const float*)d_in[0];
    // d_in[1] past_observed_values: not used by the reference math
    const float* z0 = (const float*)d_in[2];
    const float* W1 = (const float*)d_in[3];
    const float* b1 = (const float*)d_in[4];
    const float* W2 = (const float*)d_in[5];
    const float* b2 = (const float*)d_in[6];
    const float* W3 = (const float*)d_in[7];
    const float* b3 = (const float*)d_in[8];

    unsigned short* wsf = (unsigned short*)d_ws;   // 32 KB used

    prep_kernel<<<64, 256, 0, stream>>>(W1, W3, wsf);
    fm_kernel<<<200, 256, 0, stream>>>(past_target, z0, W1, b1, W2, b2, b3,
                                       wsf, (float*)d_out);
}

// Round 5
// 260.067 us; speedup vs baseline: 1.8155x; 1.0931x over previous
//
#include <hip/hip_runtime.h>

#define NB 128
#define NS 100
#define NPRED 24
#define NHID 256
#define NSTEPS 16
#define NCTX 96
// 12800 rows; 32 rows/wave (2 groups), 2 waves/block -> 200 blocks of 128 thr

typedef float f32x4 __attribute__((ext_vector_type(4)));
typedef short bf16x8 __attribute__((ext_vector_type(8)));

__device__ __forceinline__ unsigned short f2bf(float f) {
    union { float f; unsigned u; } v; v.f = f;
    return (unsigned short)((v.u + 0x7fffu + ((v.u >> 16) & 1u)) >> 16);
}
__device__ __forceinline__ unsigned pk2(float lo, float hi) {
    return (unsigned)f2bf(lo) | ((unsigned)f2bf(hi) << 16);
}
__device__ __forceinline__ bf16x8 mk8(unsigned a, unsigned b, unsigned c, unsigned d) {
    union { unsigned u[4]; bf16x8 v; } x;
    x.u[0] = a; x.u[1] = b; x.u[2] = c; x.u[3] = d;
    return x.v;
}
__device__ __forceinline__ f32x4 bf4_to_f32x4(const unsigned short* pA) {
    uint2 uu = *(const uint2*)pA;
    union { unsigned u; float f; } c0, c1, c2, c3;
    c0.u = uu.x << 16; c1.u = uu.x & 0xffff0000u;
    c2.u = uu.y << 16; c3.u = uu.y & 0xffff0000u;
    f32x4 r; r.x = c0.f; r.y = c1.f; r.z = c2.f; r.w = c3.f;
    return r;
}
__device__ __forceinline__ f32x4 relu4(f32x4 a) {
    a.x = fmaxf(a.x, 0.f); a.y = fmaxf(a.y, 0.f);
    a.z = fmaxf(a.z, 0.f); a.w = fmaxf(a.w, 0.f);
    return a;
}

// k-slot permutation within a 32-wide k-block at (lane l, elem e):
//   k_local = 16*(e>>2) + 4*(l>>4) + (e&3)
// Applied identically to A and B fragments (verified R2-R4).

// prep: W1F [0,8192) + W3F [8192,16384) permuted bf16 frag images -> d_ws (32 KB, R4-proven)
__global__ void prep_kernel(const float* __restrict__ W1,
                            const float* __restrict__ W3,
                            unsigned short* __restrict__ wsf) {
    int i = blockIdx.x * 256 + threadIdx.x;   // 0..16383
    if (i < 8192) {
        int T = i >> 9, ll = (i >> 3) & 63, e = i & 7;
        int k = 16 * (e >> 2) + 4 * (ll >> 4) + (e & 3);
        int m = 16 * T + (ll & 15);
        wsf[i] = (k <= 24) ? f2bf(W1[k * NHID + m]) : (unsigned short)0;
    } else {
        int idx = i - 8192;
        int ks = idx >> 10, T = (idx >> 9) & 1, ll = (idx >> 3) & 63, e = idx & 7;
        int k = 32 * ks + 16 * (e >> 2) + 4 * (ll >> 4) + (e & 3);
        int m = 16 * T + (ll & 15);
        wsf[i] = (m < NPRED) ? f2bf(W3[k * NPRED + m]) : (unsigned short)0;
    }
}

__global__ __launch_bounds__(128, 1) void fm_kernel(
    const float* __restrict__ past_target,
    const float* __restrict__ z0g,
    const float* __restrict__ W1, const float* __restrict__ b1,
    const float* __restrict__ W2, const float* __restrict__ b2,
    const float* __restrict__ b3,
    const unsigned short* __restrict__ wsf,
    float* __restrict__ out) {
    // LDS (ushorts): cbF [0,16384) for 4 groups | W2F [16384,81920) = 160 KiB
    __shared__ __attribute__((aligned(16))) unsigned short lds[81920];

    const int tid = threadIdx.x;   // 0..127

    // ---- cbF: fp32 cbias -> bf16 C-fragments (2 threads/row, 64 rows) ----
    {
        const int r = tid >> 1, half = tid & 1;
        const int bb = (blockIdx.x * 64 + r) & 127;
        const float* ctxp = past_target + bb * NCTX;
        float asum = 0.f;
        for (int k = 0; k < NCTX; k++) asum += fabsf(ctxp[k]);
        float inv = 1.f / fmaxf(asum * (1.f / (float)NCTX), 1e-6f);
        f32x4 acc[32];
        const float* b1p = b1 + half * 128;
#pragma unroll
        for (int u = 0; u < 32; u++) acc[u] = *(const f32x4*)(b1p + 4 * u);
        for (int k = 0; k < NCTX; k++) {
            float sx = ctxp[k] * inv;
            const f32x4* wr = (const f32x4*)(W1 + (26 + k) * NHID + half * 128);
#pragma unroll
            for (int u = 0; u < 32; u++) {
                f32x4 w = wr[u];
                acc[u].x += sx * w.x; acc[u].y += sx * w.y;
                acc[u].z += sx * w.z; acc[u].w += sx * w.w;
            }
        }
        const int G = r >> 4, pp = r & 15;
#pragma unroll
        for (int u = 0; u < 32; u++) {
            int T = half * 8 + (u >> 2), qq = u & 3;
            int base = G * 4096 + T * 256 + qq * 64 + pp * 4;
            lds[base + 0] = f2bf(acc[u].x);
            lds[base + 1] = f2bf(acc[u].y);
            lds[base + 2] = f2bf(acc[u].z);
            lds[base + 3] = f2bf(acc[u].w);
        }
    }

    // ---- W2F staging: coalesced source rows, scattered LDS stores ----
    for (int k = 0; k < 256; ++k) {
        int ks = k >> 5, kl = k & 31;
        int e = ((kl >> 4) << 2) | (kl & 3);
        int lhi = (kl >> 2) & 3;
        const float* wrow = W2 + k * 256;
#pragma unroll
        for (int mm = tid; mm < 256; mm += 128) {
            int T = mm >> 4, pp = mm & 15;
            lds[16384 + ((ks * 16 + T) * 64 + lhi * 16 + pp) * 8 + e] = f2bf(wrow[mm]);
        }
    }

    const int wave = tid >> 6;     // 0..1
    const int l = tid & 63;
    const int q = l >> 4, p = l & 15;
    const int gA = blockIdx.x * 4 + wave * 2;   // group A (grp B = gA+1)
    const int RA = gA * 16 + p, RB = RA + 16;
    const int sA = RA >> 7, bA = RA & 127;
    const int sB = RB >> 7, bB = RB & 127;

    // ---- z states (C'-layout) for both groups ----
    f32x4 zsA0, zsA1, zsB0, zsB1;
    {
        const f32x4* zrA = (const f32x4*)(z0g + RA * NPRED);
        const f32x4* zrB = (const f32x4*)(z0g + RB * NPRED);
        f32x4 zz = {0.f, 0.f, 0.f, 0.f};
        zsA0 = zrA[q]; zsA1 = zz; if (q < 2) zsA1 = zrA[4 + q];
        zsB0 = zrB[q]; zsB1 = zz; if (q < 2) zsB1 = zrB[4 + q];
    }

    // ---- b3 C-fragments fp32 (pad channels zero) ----
    f32x4 b3f0 = *(const f32x4*)(b3 + 4 * q);   // ch 4q..4q+3 < 24 ok
    f32x4 b3f1 = {0.f, 0.f, 0.f, 0.f};
    if (q < 2) b3f1 = *(const f32x4*)(b3 + 16 + 4 * q);

    __syncthreads();

    const int l8 = l * 8;
    const unsigned short* cbA_base = lds + (wave * 2) * 4096 + q * 64 + p * 4;
    const unsigned short* cbB_base = cbA_base + 4096;
    const unsigned short* w2_base = lds + 16384 + l8;
    const unsigned short* w1g = wsf + l8;
    const unsigned short* w3g = wsf + 8192 + l8;

    const float dt = 1.f / (float)NSTEPS;
#pragma unroll 1
    for (int step = 0; step < NSTEPS; step++) {
        // launder invariant base pointers so LICM can't hoist frag loads
        const unsigned short* w1p = w1g;     asm volatile("" : "+v"(w1p));
        const unsigned short* w3p = w3g;     asm volatile("" : "+v"(w3p));
        const unsigned short* w2p = w2_base; asm volatile("" : "+v"(w2p));
        const unsigned short* cbAp = cbA_base; asm volatile("" : "+v"(cbAp));
        const unsigned short* cbBp = cbB_base; asm volatile("" : "+v"(cbBp));
        const float* b2p = b2;               asm volatile("" : "+v"(b2p));

        float t = 1.f - (float)step * dt;
        float zA10 = (q == 2) ? t : zsA1.x;   // channel 24 carries t
        float zB10 = (q == 2) ? t : zsB1.x;
        bf16x8 bzA = mk8(pk2(zsA0.x, zsA0.y), pk2(zsA0.z, zsA0.w),
                         pk2(zA10, zsA1.y), pk2(zsA1.z, zsA1.w));
        bf16x8 bzB = mk8(pk2(zsB0.x, zsB0.y), pk2(zsB0.z, zsB0.w),
                         pk2(zB10, zsB1.y), pk2(zsB1.z, zsB1.w));

        // ---- layer 1: h1 = relu(z@W1z + t*w1t + cbias) ----
        unsigned bhA[32], bhB[32];
#pragma unroll
        for (int T = 0; T < 16; T++) {
            bf16x8 a = *(const bf16x8*)(w1p + T * 512);
            f32x4 cA = bf4_to_f32x4(cbAp + T * 256);
            f32x4 cB = bf4_to_f32x4(cbBp + T * 256);
            f32x4 hA = relu4(__builtin_amdgcn_mfma_f32_16x16x32_bf16(a, bzA, cA, 0, 0, 0));
            f32x4 hB = relu4(__builtin_amdgcn_mfma_f32_16x16x32_bf16(a, bzB, cB, 0, 0, 0));
            bhA[2 * T] = pk2(hA.x, hA.y); bhA[2 * T + 1] = pk2(hA.z, hA.w);
            bhB[2 * T] = pk2(hB.x, hB.y); bhB[2 * T + 1] = pk2(hB.z, hB.w);
        }

        // ---- layers 2+3 fused ----
        f32x4 vA0 = {0.f, 0.f, 0.f, 0.f}, vA1 = vA0, vB0 = vA0, vB1 = vA0;
#pragma unroll
        for (int j = 0; j < 4; j++) {
            f32x4 aA0 = {0.f, 0.f, 0.f, 0.f}, aA1 = aA0, aA2 = aA0, aA3 = aA0;
            f32x4 aB0 = aA0, aB1 = aA0, aB2 = aA0, aB3 = aA0;
#pragma unroll
            for (int ks = 0; ks < 8; ks++) {
                bf16x8 bbA = mk8(bhA[4 * ks], bhA[4 * ks + 1], bhA[4 * ks + 2], bhA[4 * ks + 3]);
                bf16x8 bbB = mk8(bhB[4 * ks], bhB[4 * ks + 1], bhB[4 * ks + 2], bhB[4 * ks + 3]);
                const unsigned short* base = w2p + (ks * 16 + 4 * j) * 512;
                bf16x8 t0 = *(const bf16x8*)(base);
                bf16x8 t1 = *(const bf16x8*)(base + 512);
                bf16x8 t2 = *(const bf16x8*)(base + 1024);
                bf16x8 t3 = *(const bf16x8*)(base + 1536);
                aA0 = __builtin_amdgcn_mfma_f32_16x16x32_bf16(t0, bbA, aA0, 0, 0, 0);
                aB0 = __builtin_amdgcn_mfma_f32_16x16x32_bf16(t0, bbB, aB0, 0, 0, 0);
                aA1 = __builtin_amdgcn_mfma_f32_16x16x32_bf16(t1, bbA, aA1, 0, 0, 0);
                aB1 = __builtin_amdgcn_mfma_f32_16x16x32_bf16(t1, bbB, aB1, 0, 0, 0);
                aA2 = __builtin_amdgcn_mfma_f32_16x16x32_bf16(t2, bbA, aA2, 0, 0, 0);
                aB2 = __builtin_amdgcn_mfma_f32_16x16x32_bf16(t2, bbB, aB2, 0, 0, 0);
                aA3 = __builtin_amdgcn_mfma_f32_16x16x32_bf16(t3, bbA, aA3, 0, 0, 0);
                aB3 = __builtin_amdgcn_mfma_f32_16x16x32_bf16(t3, bbB, aB3, 0, 0, 0);
            }
            // bias (fp32 VALU) + relu + pack
            f32x4 bf0 = *(const f32x4*)(b2p + (4 * j + 0) * 16 + 4 * q);
            f32x4 bf1 = *(const f32x4*)(b2p + (4 * j + 1) * 16 + 4 * q);
            f32x4 bf2 = *(const f32x4*)(b2p + (4 * j + 2) * 16 + 4 * q);
            f32x4 bf3 = *(const f32x4*)(b2p + (4 * j + 3) * 16 + 4 * q);
            f32x4 hA0 = relu4(aA0 + bf0), hA1 = relu4(aA1 + bf1);
            f32x4 hA2 = relu4(aA2 + bf2), hA3 = relu4(aA3 + bf3);
            f32x4 hB0 = relu4(aB0 + bf0), hB1 = relu4(aB1 + bf1);
            f32x4 hB2 = relu4(aB2 + bf2), hB3 = relu4(aB3 + bf3);
            bf16x8 b3aA = mk8(pk2(hA0.x, hA0.y), pk2(hA0.z, hA0.w), pk2(hA1.x, hA1.y), pk2(hA1.z, hA1.w));
            bf16x8 b3bA = mk8(pk2(hA2.x, hA2.y), pk2(hA2.z, hA2.w), pk2(hA3.x, hA3.y), pk2(hA3.z, hA3.w));
            bf16x8 b3aB = mk8(pk2(hB0.x, hB0.y), pk2(hB0.z, hB0.w), pk2(hB1.x, hB1.y), pk2(hB1.z, hB1.w));
            bf16x8 b3bB = mk8(pk2(hB2.x, hB2.y), pk2(hB2.z, hB2.w), pk2(hB3.x, hB3.y), pk2(hB3.z, hB3.w));
            const unsigned short* w3b = w3p + 2 * j * 1024;
            bf16x8 w30 = *(const bf16x8*)(w3b);
            bf16x8 w31 = *(const bf16x8*)(w3b + 512);
            bf16x8 w32 = *(const bf16x8*)(w3b + 1024);
            bf16x8 w33 = *(const bf16x8*)(w3b + 1536);
            vA0 = __builtin_amdgcn_mfma_f32_16x16x32_bf16(w30, b3aA, vA0, 0, 0, 0);
            vA1 = __builtin_amdgcn_mfma_f32_16x16x32_bf16(w31, b3aA, vA1, 0, 0, 0);
            vA0 = __builtin_amdgcn_mfma_f32_16x16x32_bf16(w32, b3bA, vA0, 0, 0, 0);
            vA1 = __builtin_amdgcn_mfma_f32_16x16x32_bf16(w33, b3bA, vA1, 0, 0, 0);
            vB0 = __builtin_amdgcn_mfma_f32_16x16x32_bf16(w30, b3aB, vB0, 0, 0, 0);
            vB1 = __builtin_amdgcn_mfma_f32_16x16x32_bf16(w31, b3aB, vB1, 0, 0, 0);
            vB0 = __builtin_amdgcn_mfma_f32_16x16x32_bf16(w32, b3bB, vB0, 0, 0, 0);
            vB1 = __builtin_amdgcn_mfma_f32_16x16x32_bf16(w33, b3bB, vB1, 0, 0, 0);
        }

        // ---- Euler update: z -= dt*(v + b3) (pad: v==0 and b3f==0) ----
        zsA0.x -= dt * (vA0.x + b3f0.x); zsA0.y -= dt * (vA0.y + b3f0.y);
        zsA0.z -= dt * (vA0.z + b3f0.z); zsA0.w -= dt * (vA0.w + b3f0.w);
        zsA1.x -= dt * (vA1.x + b3f1.x); zsA1.y -= dt * (vA1.y + b3f1.y);
        zsA1.z -= dt * (vA1.z + b3f1.z); zsA1.w -= dt * (vA1.w + b3f1.w);
        zsB0.x -= dt * (vB0.x + b3f0.x); zsB0.y -= dt * (vB0.y + b3f0.y);
        zsB0.z -= dt * (vB0.z + b3f0.z); zsB0.w -= dt * (vB0.w + b3f0.w);
        zsB1.x -= dt * (vB1.x + b3f1.x); zsB1.y -= dt * (vB1.y + b3f1.y);
        zsB1.z -= dt * (vB1.z + b3f1.z); zsB1.w -= dt * (vB1.w + b3f1.w);
    }

    // ---- loc per group (post-loop to keep loop pressure low) ----
    float asumA = 0.f, asumB = 0.f;
    {
        const float* ca = past_target + bA * NCTX;
        const float* cbp_ = past_target + bB * NCTX;
        for (int k = 0; k < NCTX; k++) { asumA += fabsf(ca[k]); asumB += fabsf(cbp_[k]); }
    }
    float locA = fmaxf(asumA * (1.f / (float)NCTX), 1e-6f);
    float locB = fmaxf(asumB * (1.f / (float)NCTX), 1e-6f);

    // ---- store: out[b][s][c] = z[c] * loc ----
    {
        float* op = out + bA * (NS * NPRED) + sA * NPRED;
        f32x4 o0 = zsA0 * locA;
        *(f32x4*)(op + 4 * q) = o0;
        if (q < 2) { f32x4 o1 = zsA1 * locA; *(f32x4*)(op + 16 + 4 * q) = o1; }
    }
    {
        float* op = out + bB * (NS * NPRED) + sB * NPRED;
        f32x4 o0 = zsB0 * locB;
        *(f32x4*)(op + 4 * q) = o0;
        if (q < 2) { f32x4 o1 = zsB1 * locB; *(f32x4*)(op + 16 + 4 * q) = o1; }
    }
}

extern "C" void kernel_launch(void* const* d_in, const int* in_sizes, int n_in,
                              void* d_out, int out_size, void* d_ws, size_t ws_size,
                              hipStream_t stream) {
    const float* past_target = (const float*)d_in[0];
    // d_in[1] past_observed_values: not used by the reference math
    const float* z0 = (const float*)d_in[2];
    const float* W1 = (const float*)d_in[3];
    const float* b1 = (const float*)d_in[4];
    const float* W2 = (const float*)d_in[5];
    const float* b2 = (const float*)d_in[6];
    const float* W3 = (const float*)d_in[7];
    const float* b3 = (const float*)d_in[8];

    unsigned short* wsf = (unsigned short*)d_ws;   // 32 KB used (R4-proven)

    prep_kernel<<<64, 256, 0, stream>>>(W1, W3, wsf);
    fm_kernel<<<200, 128, 0, stream>>>(past_target, z0, W1, b1, W2, b2, b3,
                                       wsf, (float*)d_out);
}